// Round 1
// 380.470 us; speedup vs baseline: 1.0802x; 1.0802x over previous
//
#include <hip/hip_runtime.h>
#include <hip/hip_bf16.h>

// Problem constants
#define B_    2
#define S_    2048
#define E_    2048
#define H_    16
#define HKV_  4
#define D_    128
#define QKV_  3072   // D*(H+2*HKV)

#define LOG2E  1.4426950408889634f
#define SCALE  0.08838834764831845f   // 1/sqrt(128)
#define SL     0.127517431f           // SCALE * LOG2E

typedef __attribute__((ext_vector_type(8))) short short8;   // 8 x bf16 (4 VGPRs)
typedef __attribute__((ext_vector_type(4))) float floatx4;  // MFMA 16x16 accumulator

typedef __attribute__((address_space(1))) const unsigned int gu32;
typedef __attribute__((address_space(3))) unsigned int lu32;

__device__ __forceinline__ void load_lds16(const unsigned short* g, unsigned short* l) {
    // async global->LDS, 16B/lane, dest = wave-uniform base + lane*16 (m97/m104)
    __builtin_amdgcn_global_load_lds((gu32*)g, (lu32*)l, 16, 0, 0);
}

__device__ __forceinline__ float b2f(unsigned short u) {
    union { unsigned int i; float f; } v; v.i = ((unsigned int)u) << 16; return v.f;
}
__device__ __forceinline__ unsigned short f2b(float f) {
    union { float f; unsigned int i; } v; v.f = f;
    unsigned int r = v.i + 0x7FFFu + ((v.i >> 16) & 1u);  // round-to-nearest-even
    return (unsigned short)(r >> 16);
}
__device__ __forceinline__ unsigned int fbits(float f) {
    union { float f; unsigned int i; } v; v.f = f; return v.i;
}
__device__ __forceinline__ float bits2f(unsigned int i) {
    union { unsigned int i; float f; } v; v.i = i; return v.f;
}

// counted vmcnt wait (never 0 in steady state; T4)
template<int N> __device__ __forceinline__ void waitcnt_vm() {
    static_assert(N >= 0 && N <= 8, "vmcnt out of range");
    if constexpr (N == 0) asm volatile("s_waitcnt vmcnt(0)" ::: "memory");
    else if constexpr (N == 1) asm volatile("s_waitcnt vmcnt(1)" ::: "memory");
    else if constexpr (N == 2) asm volatile("s_waitcnt vmcnt(2)" ::: "memory");
    else if constexpr (N == 3) asm volatile("s_waitcnt vmcnt(3)" ::: "memory");
    else if constexpr (N == 4) asm volatile("s_waitcnt vmcnt(4)" ::: "memory");
    else if constexpr (N == 5) asm volatile("s_waitcnt vmcnt(5)" ::: "memory");
    else if constexpr (N == 6) asm volatile("s_waitcnt vmcnt(6)" ::: "memory");
    else if constexpr (N == 7) asm volatile("s_waitcnt vmcnt(7)" ::: "memory");
    else asm volatile("s_waitcnt vmcnt(8)" ::: "memory");
}

// ---------------------------------------------------------------------------
// f32 -> bf16 convert (contiguous). 4 elems/thread.
// ---------------------------------------------------------------------------
__global__ __launch_bounds__(256) void cvt_f32_bf16(
    const float* __restrict__ src, unsigned short* __restrict__ dst, int n)
{
    int i = (blockIdx.x * 256 + threadIdx.x) * 4;
    if (i + 3 < n) {
        float4 v = *(const float4*)&src[i];
        ushort4 o;
        o.x = f2b(v.x); o.y = f2b(v.y); o.z = f2b(v.z); o.w = f2b(v.w);
        *(ushort4*)&dst[i] = o;
    }
}

// ---------------------------------------------------------------------------
// f32 -> bf16 transpose: src[R][C] f32 -> dst[C][R] bf16. block (32,8).
// ---------------------------------------------------------------------------
__global__ __launch_bounds__(256) void transpose_f32_bf16(
    const float* __restrict__ src, unsigned short* __restrict__ dst,
    int R, int C)
{
    __shared__ unsigned short tile[32][33];
    const int c0 = blockIdx.x * 32, r0 = blockIdx.y * 32;
    const int tx = threadIdx.x, ty = threadIdx.y;
    #pragma unroll
    for (int i = 0; i < 4; i++)
        tile[ty + 8 * i][tx] = f2b(src[(size_t)(r0 + ty + 8 * i) * C + c0 + tx]);
    __syncthreads();
    #pragma unroll
    for (int i = 0; i < 4; i++)
        dst[(size_t)(c0 + ty + 8 * i) * R + r0 + tx] = tile[tx][ty + 8 * i];
}

// ---------------------------------------------------------------------------
// bf16 -> bf16 batched transpose (for V): src[batch][R][C] -> dst[batch][C][R]
// ---------------------------------------------------------------------------
__global__ __launch_bounds__(256) void transpose_bf16(
    const unsigned short* __restrict__ src, unsigned short* __restrict__ dst,
    int R, int C)
{
    __shared__ unsigned short tile[32][33];
    const size_t boff = (size_t)blockIdx.z * R * C;
    src += boff; dst += boff;
    const int c0 = blockIdx.x * 32, r0 = blockIdx.y * 32;
    const int tx = threadIdx.x, ty = threadIdx.y;
    #pragma unroll
    for (int i = 0; i < 4; i++)
        tile[ty + 8 * i][tx] = src[(size_t)(r0 + ty + 8 * i) * C + c0 + tx];
    __syncthreads();
    #pragma unroll
    for (int i = 0; i < 4; i++)
        dst[(size_t)(c0 + ty + 8 * i) * R + r0 + tx] = tile[tx][ty + 8 * i];
}

// ---------------------------------------------------------------------------
// 8-phase 256-wide MFMA GEMM (m194-m204 template, plain HIP).
//   C[M][N] = A[M][K] @ Bt[N][K]^T + bias[N]
// BM=256 fixed; BN in {256,128}. 512 threads = 8 waves, wave grid WM x WN.
// K-tile BK=64 double-buffered; each K-tile computed in 4 phases (one wave-tile
// quadrant x K=64 each); each phase stages one 16/8 KB unit of the NEXT K-tile
// via global_load_lds (linear LDS dest + inverse-swizzled global source,
// rule #21); counted vmcnt keeps 2-3 units in flight across barriers (T3+T4);
// setprio(1) around each MFMA cluster (T5); XCD-chunked block swizzle (T1).
//
// LDS granule swizzle: 128-B rows of the [rows][64] bf16 tile store logical
// 16B-granule g at physical granule g ^ (row&7). Fragment ds_read_b128 of a
// column slice then has every 8 consecutive lanes hitting all 8 granules ->
// conflict-free (each 8-lane LDS cycle covers all 32 banks).
//
// vmcnt accounting (stage order [A0,B0,B1,A1], needs p0:{A0,B0} p1:{A0,B1}
// p2:{A1,B0} p3:{A1,B1}; LA/LB = loads per A/B unit): guard before the barrier
// that precedes the reads needing the data:
//   end p0 -> 2*LA,  end p1 -> LA+LB,  end p2 -> LA+2*LB,  end p3 -> LA+LB.
// In-order vmcnt retirement (m135) makes any hoisted-issue strictly safer.
// Full vmcnt(0) drain only once, before the peeled last K-tile.
// ---------------------------------------------------------------------------
template<int WR, int QR, int LX>
__device__ __forceinline__ void stage_unit8(
    const unsigned short* __restrict__ G, unsigned short* ls,
    int uu, int g0, int K, int k0, int wave, int lane)
{
    // unit uu = rows { w*WR + uu*QR + [0,QR) } for each wave-row w.
    // chunk c = 1 KB = 8 rows; per-lane source granule inverse-swizzled.
    #pragma unroll
    for (int l = 0; l < LX; ++l) {
        const int c    = wave * LX + l;
        const int rr   = c / (QR / 8);
        const int row0 = rr * WR + uu * QR + (c % (QR / 8)) * 8;
        const int srow = row0 + (lane >> 3);
        const int sg   = (lane & 7) ^ (lane >> 3);
        load_lds16(&G[(size_t)(g0 + srow) * K + k0 + sg * 8], &ls[row0 * 64]);
    }
}

template<int BN, int WM, int WN, int OUTF32>
__global__ __launch_bounds__(512, 2) void gemm8(
    const unsigned short* __restrict__ A, const unsigned short* __restrict__ Bt,
    const float* __restrict__ bias, void* __restrict__ Cv,
    int M, int N, int K)
{
    constexpr int BM   = 256;
    constexpr int WMR  = BM / WM, WNR = BN / WN;   // wave tile
    constexpr int QMR  = WMR / 2, QNR = WNR / 2;   // quadrant
    constexpr int FM   = QMR / 16, FN = QNR / 16;  // frags per quadrant
    constexpr int LA   = BM / 128, LB = BN / 128;  // loads per unit
    constexpr int TILE = (BM + BN) * 64;           // ushorts per buffer

    __shared__ unsigned short lds[2 * TILE];       // 128 KiB (BN=256) / 96 KiB

    const int tid  = threadIdx.x;
    const int wave = tid >> 6, lane = tid & 63;
    const int ln   = lane & 15, kq = lane >> 4;
    const int wm   = wave / WN, wn = wave % WN;

    // T1: XCD-chunked swizzle (valid: nwg % 8 == 0 for both shapes)
    const int nwg = gridDim.x;
    const int wg  = (blockIdx.x & 7) * (nwg >> 3) + (blockIdx.x >> 3);
    const int nbn = N / BN;
    const int m0  = (wg / nbn) * BM, n0 = (wg % nbn) * BN;

    floatx4 acc[2 * FM][2 * FN];
    #pragma unroll
    for (int i = 0; i < 2 * FM; ++i)
        #pragma unroll
        for (int j = 0; j < 2 * FN; ++j) {
            acc[i][j][0] = 0.f; acc[i][j][1] = 0.f;
            acc[i][j][2] = 0.f; acc[i][j][3] = 0.f;
        }

    // prologue: stage K-tile 0 into buf 0, order [A0,B0,B1,A1]
    stage_unit8<WMR, QMR, LA>(A,  &lds[0],       0, m0, K, 0, wave, lane);
    stage_unit8<WNR, QNR, LB>(Bt, &lds[BM * 64], 0, n0, K, 0, wave, lane);
    stage_unit8<WNR, QNR, LB>(Bt, &lds[BM * 64], 1, n0, K, 0, wave, lane);
    stage_unit8<WMR, QMR, LA>(A,  &lds[0],       1, m0, K, 0, wave, lane);
    waitcnt_vm<LA + LB>();          // A0,B0 landed (B1,A1 still in flight)
    __builtin_amdgcn_s_barrier();

    const int NT = K >> 6;
    int cur = 0;

    for (int t = 0; t < NT - 1; ++t) {
        const unsigned short* Asp = &lds[cur * TILE];
        const unsigned short* Bsp = Asp + BM * 64;
        unsigned short* Ssp = &lds[(cur ^ 1) * TILE];
        const int k1 = (t + 1) << 6;
        #pragma unroll
        for (int p = 0; p < 4; ++p) {
            const int qm = p >> 1, qn = p & 1;
            // ds-read this quadrant's fragments (swizzled granule)
            short8 af[2][FM], bg[2][FN];
            #pragma unroll
            for (int ks = 0; ks < 2; ++ks) {
                #pragma unroll
                for (int i = 0; i < FM; ++i)
                    af[ks][i] = *(const short8*)&Asp[(wm * WMR + qm * QMR + i * 16 + ln) * 64
                                                     + (((ks * 4 + kq) ^ (ln & 7)) * 8)];
                #pragma unroll
                for (int j = 0; j < FN; ++j)
                    bg[ks][j] = *(const short8*)&Bsp[(wn * WNR + qn * QNR + j * 16 + ln) * 64
                                                     + (((ks * 4 + kq) ^ (ln & 7)) * 8)];
            }
            // stage one unit of K-tile t+1 into the other buffer
            if (p == 0)      stage_unit8<WMR, QMR, LA>(A,  Ssp,           0, m0, K, k1, wave, lane);
            else if (p == 1) stage_unit8<WNR, QNR, LB>(Bt, Ssp + BM * 64, 0, n0, K, k1, wave, lane);
            else if (p == 2) stage_unit8<WNR, QNR, LB>(Bt, Ssp + BM * 64, 1, n0, K, k1, wave, lane);
            else             stage_unit8<WMR, QMR, LA>(A,  Ssp,           1, m0, K, k1, wave, lane);
            __builtin_amdgcn_s_barrier();
            __builtin_amdgcn_s_setprio(1);
            #pragma unroll
            for (int ks = 0; ks < 2; ++ks)
                #pragma unroll
                for (int i = 0; i < FM; ++i)
                    #pragma unroll
                    for (int j = 0; j < FN; ++j)
                        acc[qm * FM + i][qn * FN + j] = __builtin_amdgcn_mfma_f32_16x16x32_bf16(
                            af[ks][i], bg[ks][j], acc[qm * FM + i][qn * FN + j], 0, 0, 0);
            __builtin_amdgcn_s_setprio(0);
            // counted wait guarding the NEXT phase's ds_reads (never 0)
            if (p == 0)      waitcnt_vm<2 * LA>();
            else if (p == 1) waitcnt_vm<LA + LB>();
            else if (p == 2) waitcnt_vm<LA + 2 * LB>();
            else             waitcnt_vm<LA + LB>();
            __builtin_amdgcn_s_barrier();
        }
        cur ^= 1;
    }

    // peeled last K-tile: drain once, then pure compute (no barriers needed)
    asm volatile("s_waitcnt vmcnt(0)" ::: "memory");
    __builtin_amdgcn_s_barrier();
    {
        const unsigned short* Asp = &lds[cur * TILE];
        const unsigned short* Bsp = Asp + BM * 64;
        #pragma unroll
        for (int p = 0; p < 4; ++p) {
            const int qm = p >> 1, qn = p & 1;
            short8 af[2][FM], bg[2][FN];
            #pragma unroll
            for (int ks = 0; ks < 2; ++ks) {
                #pragma unroll
                for (int i = 0; i < FM; ++i)
                    af[ks][i] = *(const short8*)&Asp[(wm * WMR + qm * QMR + i * 16 + ln) * 64
                                                     + (((ks * 4 + kq) ^ (ln & 7)) * 8)];
                #pragma unroll
                for (int j = 0; j < FN; ++j)
                    bg[ks][j] = *(const short8*)&Bsp[(wn * WNR + qn * QNR + j * 16 + ln) * 64
                                                     + (((ks * 4 + kq) ^ (ln & 7)) * 8)];
            }
            __builtin_amdgcn_s_setprio(1);
            #pragma unroll
            for (int ks = 0; ks < 2; ++ks)
                #pragma unroll
                for (int i = 0; i < FM; ++i)
                    #pragma unroll
                    for (int j = 0; j < FN; ++j)
                        acc[qm * FM + i][qn * FN + j] = __builtin_amdgcn_mfma_f32_16x16x32_bf16(
                            af[ks][i], bg[ks][j], acc[qm * FM + i][qn * FN + j], 0, 0, 0);
            __builtin_amdgcn_s_setprio(0);
        }
    }

    // epilogue: bias add + store (C/D map: col=ln, row=kq*4+r)
    #pragma unroll
    for (int nj = 0; nj < 2 * FN; ++nj) {
        const int col = n0 + wn * WNR + nj * 16 + ln;
        const float bv = bias[col];
        #pragma unroll
        for (int mi = 0; mi < 2 * FM; ++mi) {
            const int rowb = m0 + wm * WMR + mi * 16 + kq * 4;
            #pragma unroll
            for (int r = 0; r < 4; ++r) {
                const float val = acc[mi][nj][r] + bv;
                if (OUTF32) ((float*)Cv)[(size_t)(rowb + r) * N + col] = val;
                else ((unsigned short*)Cv)[(size_t)(rowb + r) * N + col] = f2b(val);
            }
        }
    }
}

// ---------------------------------------------------------------------------
// Fused depthwise causal conv (DCONV=4) + RoPE + q/k/v split-scatter.
// ---------------------------------------------------------------------------
__device__ __forceinline__ float conv_at(
    const unsigned short* __restrict__ qb, const float* __restrict__ cw,
    const float* __restrict__ cb, int s, int c)
{
    float acc = cb[c];
    const float* w = cw + c * 4;
    #pragma unroll
    for (int t = 0; t < 4; t++) {
        int sp = s - 3 + t;
        if (sp >= 0) acc += b2f(qb[(size_t)sp * QKV_ + c]) * w[t];
    }
    return acc;
}

__global__ __launch_bounds__(256) void conv_rot(
    const unsigned short* __restrict__ qkv, const float* __restrict__ cw,
    const float* __restrict__ cb, unsigned short* __restrict__ qo,
    unsigned short* __restrict__ ko, unsigned short* __restrict__ vo)
{
    const int bs = blockIdx.x;
    const int b = bs >> 11, s = bs & 2047;
    const unsigned short* qb = qkv + (size_t)b * S_ * QKV_;

    for (int it = threadIdx.x; it < 1792; it += 256) {
        if (it < 1280) {
            const int isq = it < 1024;
            const int rel = isq ? it : it - 1024;
            const int head = rel >> 6, d = rel & 63;
            const int c1 = (isq ? head * 128 : 2048 + head * 128) + d;
            float x1 = conv_at(qb, cw, cb, s, c1);
            float x2 = conv_at(qb, cw, cb, s, c1 + 64);
            float inv = exp2f((float)d * -0.2076205059304601f);  // 10000^(-d/64)
            float ang = (float)s * inv;
            float sn, cs;
            __sincosf(ang, &sn, &cs);   // fast-math: hw v_sin/v_cos, bf16-accurate
            float r1 = x1 * cs - x2 * sn;
            float r2 = x2 * cs + x1 * sn;
            unsigned short* dst = isq
                ? qo + ((size_t)(b * H_   + head) * S_ + s) * D_
                : ko + ((size_t)(b * HKV_ + head) * S_ + s) * D_;
            dst[d]      = f2b(r1);
            dst[d + 64] = f2b(r2);
        } else {
            const int idx = it - 1280;          // 0..511
            const int g = idx >> 7, d = idx & 127;
            float vv = conv_at(qb, cw, cb, s, 2560 + idx);
            vo[((size_t)(b * HKV_ + g) * S_ + s) * D_ + d] = f2b(vv);
        }
    }
}

// ---------------------------------------------------------------------------
// Flash attention (causal, GQA rep=4). Grid (h=16, qy=32, b=2), qt = 31-qy:
// dispatch order is monotone big-work-first (LPT) -> greedy backfill balances
// CUs without pairing; 1024 blocks = 4/CU. LDS exactly 40960 B so 4 blocks
// fit; __launch_bounds__(256,4) caps VGPR at 128 for 4 waves/SIMD.
// All LDS tiles XOR-swizzled at 16B granule: frag reads 2-way (free, m136).
// ---------------------------------------------------------------------------
__global__ __launch_bounds__(256, 4) void attn(
    const unsigned short* __restrict__ q, const unsigned short* __restrict__ k,
    const unsigned short* __restrict__ vT, unsigned short* __restrict__ ctx)
{
    __shared__ unsigned short Ks[64 * 128];    // 16 KB, swizzled
    __shared__ unsigned short Vs[128 * 64];    // 16 KB, swizzled
    __shared__ unsigned short Ps[4][16][64];   // 8 KB, per-wave, swizzled

    const int h = blockIdx.x, qt = 31 - blockIdx.y, b = blockIdx.z, g = h >> 2;
    const int tid = threadIdx.x, wave = tid >> 6, lane = tid & 63;
    const int ln = lane & 15, kq = lane >> 4;

    const unsigned short* qh = q  + (size_t)(b * H_   + h) * S_ * D_;
    const unsigned short* kh = k  + (size_t)(b * HKV_ + g) * S_ * D_;
    const unsigned short* vh = vT + (size_t)(b * HKV_ + g) * D_ * S_;

    // staging geometry (per wave, 4 chunks of 1 KB each for K and V)
    const int rK = (lane >> 4);          // +4*chunk rows of K per chunk
    const int pK = lane & 15;            // phys granule within K row
    const int rV = (lane >> 3);          // +8*chunk rows of V per chunk
    const int pV = lane & 7;             // phys granule within V row

    const int qrow0 = qt * 64 + wave * 16;

    short8 qf[4];
    #pragma unroll
    for (int f = 0; f < 4; f++)
        qf[f] = *(const short8*)&qh[(size_t)(qrow0 + ln) * D_ + f * 32 + kq * 8];

    floatx4 o[8];
    #pragma unroll
    for (int i = 0; i < 8; i++) { o[i][0] = 0.f; o[i][1] = 0.f; o[i][2] = 0.f; o[i][3] = 0.f; }
    float mr = -INFINITY, lr = 0.f;

    for (int kt = 0; kt <= qt; kt++) {
        __syncthreads();   // previous tile's LDS reads complete
        #pragma unroll
        for (int c = 0; c < 4; c++) {
            const int chunk = wave * 4 + c;        // 0..15
            // K: rows r = chunk*4 + rK, logical granule = pK ^ (r&15)
            int r  = chunk * 4 + rK;
            int gc = pK ^ (r & 15);
            load_lds16(&kh[(size_t)(kt * 64 + r) * D_ + gc * 8], &Ks[chunk * 512]);
            // V: rows rv = chunk*8 + rV, logical granule = pV ^ (rv&7)
            int rv = chunk * 8 + rV;
            int gv = pV ^ (rv & 7);
            load_lds16(&vh[(size_t)rv * S_ + kt * 64 + gv * 8], &Vs[chunk * 512]);
        }
        __syncthreads();   // vmcnt drained before barrier

        // S^T = K Q^T : per lane, 16 kv values for q-row (qrow0 + ln)
        floatx4 scv[4];
        #pragma unroll
        for (int nb = 0; nb < 4; nb++) { scv[nb][0]=0.f; scv[nb][1]=0.f; scv[nb][2]=0.f; scv[nb][3]=0.f; }
        #pragma unroll
        for (int ks = 0; ks < 4; ks++) {
            #pragma unroll
            for (int nb = 0; nb < 4; nb++) {
                short8 kf = *(const short8*)&Ks[(nb * 16 + ln) * 128 + (((ks * 4 + kq) ^ ln) * 8)];
                scv[nb] = __builtin_amdgcn_mfma_f32_16x16x32_bf16(kf, qf[ks], scv[nb], 0, 0, 0);
            }
        }

        // causal mask on diagonal tile:
        // kv_local = nb*16+kq*4+r, q_local (in 64-tile) = wave*16 + ln
        if (kt == qt) {
            const int qloc = wave * 16 + ln;
            #pragma unroll
            for (int nb = 0; nb < 4; nb++)
                #pragma unroll
                for (int r = 0; r < 4; r++)
                    if (nb * 16 + kq * 4 + r > qloc) scv[nb][r] = -INFINITY;
        }

        // per-lane online softmax (raw-score domain; SL folds scale+log2e)
        float mx = -INFINITY;
        #pragma unroll
        for (int nb = 0; nb < 4; nb++) {
            float a0 = fmaxf(scv[nb][0], scv[nb][1]);
            float a1 = fmaxf(scv[nb][2], scv[nb][3]);
            mx = fmaxf(mx, fmaxf(a0, a1));
        }
        mx = fmaxf(mx, __shfl_xor(mx, 16));
        mx = fmaxf(mx, __shfl_xor(mx, 32));
        float mt = fmaxf(mr, mx);
        float al = exp2f((mr - mt) * SL);
        mr = mt;

        // p truncated to bf16 (denominator sums the SAME truncated values);
        // paired ds_write_b32 into granule-swizzled Ps (phys gran = g^(ln&7))
        float rs = 0.f;
        #pragma unroll
        for (int nb = 0; nb < 4; nb++) {
            const int gct = 2 * nb + (kq >> 1);
            const int pbase = ((gct ^ (ln & 7)) << 3) + ((kq & 1) << 2);
            #pragma unroll
            for (int rr = 0; rr < 2; rr++) {
                unsigned int u0 = fbits(exp2f((scv[nb][2 * rr]     - mt) * SL));
                unsigned int u1 = fbits(exp2f((scv[nb][2 * rr + 1] - mt) * SL));
                rs += bits2f(u0 & 0xFFFF0000u) + bits2f(u1 & 0xFFFF0000u);
                *(unsigned int*)&Ps[wave][ln][pbase + 2 * rr] =
                    (u0 >> 16) | (u1 & 0xFFFF0000u);
            }
        }
        rs += __shfl_xor(rs, 16);
        rs += __shfl_xor(rs, 32);
        lr = lr * al + rs;

        // broadcast alpha to the o-layout rows (q_local = kq*4+r)
        float alr[4];
        #pragma unroll
        for (int r = 0; r < 4; r++) alr[r] = __shfl(al, kq * 4 + r);
        #pragma unroll
        for (int dn = 0; dn < 8; dn++)
            #pragma unroll
            for (int r = 0; r < 4; r++) o[dn][r] *= alr[r];

        // O += P V  (Ps wave-private: lgkmcnt ordering suffices, no barrier)
        short8 pa0 = *(const short8*)&Ps[wave][ln][(kq ^ (ln & 7)) << 3];
        short8 pa1 = *(const short8*)&Ps[wave][ln][((4 + kq) ^ (ln & 7)) << 3];
        #pragma unroll
        for (int dn = 0; dn < 8; dn++) {
            short8 b0 = *(const short8*)&Vs[(dn * 16 + ln) * 64 + ((kq ^ (ln & 7)) * 8)];
            o[dn] = __builtin_amdgcn_mfma_f32_16x16x32_bf16(pa0, b0, o[dn], 0, 0, 0);
            short8 b1 = *(const short8*)&Vs[(dn * 16 + ln) * 64 + (((4 + kq) ^ (ln & 7)) * 8)];
            o[dn] = __builtin_amdgcn_mfma_f32_16x16x32_bf16(pa1, b1, o[dn], 0, 0, 0);
        }
    }

    // epilogue: broadcast 1/l to o-layout rows, write ctx[b*S+s][h*D+d]
    float lrr[4];
    #pragma unroll
    for (int r = 0; r < 4; r++) lrr[r] = 1.0f / __shfl(lr, kq * 4 + r);
    #pragma unroll
    for (int r = 0; r < 4; r++) {
        size_t rowoff = (size_t)(b * S_ + qt * 64 + wave * 16 + kq * 4 + r) * (H_ * D_) + h * D_;
        #pragma unroll
        for (int dn = 0; dn < 8; dn++)
            ctx[rowoff + dn * 16 + ln] = f2b(o[dn][r] * lrr[r]);
    }
}

// ---------------------------------------------------------------------------
// kernel_launch — ws layout (bf16 buffers, total 88 MB):
//   WtIn [3072][2048] @0 (12MB) | WtOut [2048][2048] @12MB (8MB)
//   x16 [4096][2048] @20MB (16MB, ctx aliases after GEMM1)
//   qkv [4096][3072] @36MB (24MB) | q @60MB (16MB) | k @76MB (4MB)
//   v @80MB (4MB) | vT @84MB (4MB)
// ---------------------------------------------------------------------------
extern "C" void kernel_launch(void* const* d_in, const int* in_sizes, int n_in,
                              void* d_out, int out_size, void* d_ws, size_t ws_size,
                              hipStream_t stream)
{
    const float* x     = (const float*)d_in[0];
    const float* W_in  = (const float*)d_in[1];
    const float* b_in  = (const float*)d_in[2];
    const float* cw    = (const float*)d_in[3];
    const float* cb    = (const float*)d_in[4];
    const float* W_out = (const float*)d_in[5];
    const float* b_out = (const float*)d_in[6];
    float* out = (float*)d_out;
    char* ws = (char*)d_ws;

    const size_t MB = 1024 * 1024;
    unsigned short* WtIn  = (unsigned short*)(ws);
    unsigned short* WtOut = (unsigned short*)(ws + 12 * MB);
    unsigned short* x16   = (unsigned short*)(ws + 20 * MB);
    unsigned short* qkv   = (unsigned short*)(ws + 36 * MB);
    unsigned short* qa    = (unsigned short*)(ws + 60 * MB);
    unsigned short* ka    = (unsigned short*)(ws + 76 * MB);
    unsigned short* va    = (unsigned short*)(ws + 80 * MB);
    unsigned short* vTa   = (unsigned short*)(ws + 84 * MB);
    unsigned short* ctx   = (unsigned short*)(ws + 20 * MB);  // aliases x16

    dim3 tb(32, 8);
    hipLaunchKernelGGL(cvt_f32_bf16, dim3(8192), dim3(256), 0, stream, x, x16, 8388608);
    hipLaunchKernelGGL(transpose_f32_bf16, dim3(96, 64), tb, 0, stream, W_in,  WtIn,  2048, 3072);
    hipLaunchKernelGGL(transpose_f32_bf16, dim3(64, 64), tb, 0, stream, W_out, WtOut, 2048, 2048);
    // GEMM1: 4096x3072x2048, 256x256 tiles -> 16x12 = 192 blocks (192%8==0)
    hipLaunchKernelGGL((gemm8<256, 2, 4, 0>), dim3(192), dim3(512), 0, stream,
                       x16, WtIn, b_in, (void*)qkv, 4096, 3072, 2048);
    hipLaunchKernelGGL(conv_rot, dim3(4096), dim3(256), 0, stream, qkv, cw, cb, qa, ka, va);
    hipLaunchKernelGGL(transpose_bf16, dim3(4, 64, 8), tb, 0, stream, va, vTa, 2048, 128);
    hipLaunchKernelGGL(attn, dim3(16, 32, 2), dim3(256), 0, stream, qa, ka, vTa, ctx);
    // GEMM2: 4096x2048x2048, 256x128 tiles -> 16x16 = 256 blocks (full device)
    hipLaunchKernelGGL((gemm8<128, 4, 2, 1>), dim3(256), dim3(512), 0, stream,
                       ctx, WtOut, b_out, (void*)out, 4096, 2048, 2048);
}